// Round 11
// baseline (592.115 us; speedup 1.0000x reference)
//
#include <hip/hip_runtime.h>
#include <hip/hip_bf16.h>

#define N_NODES 50000
#define N_EDGES 1600000
#define DIM 128
#define N_LAYERS 5
#define NEG 0.2f

#define NBKT 196          // dst >> 8
#define BCAP_A 9472       // arena cap per bucket (mean 8163)
#define PBLK 196          // partition blocks (all CUs)
#define EPB 8192          // edges per partition block
#define SEGCAP 12288      // k_scat staging entries (u32)
#define SENT N_NODES      // sentinel src row for padded edges
#define LOG2E 1.4426950408889634f

typedef unsigned short u16;
typedef unsigned char u8;
typedef unsigned int u32;
using short8 = __attribute__((ext_vector_type(8))) short;
using f32x4  = __attribute__((ext_vector_type(4))) float;
typedef float f32x2 __attribute__((ext_vector_type(2)));

union FragU { uint4 u; short8 s; };

// ---------- helpers ----------
__device__ __forceinline__ f32x2 bf2v(u32 u) {
    union { u32 i; float f; } lo, hi;
    lo.i = u << 16;
    hi.i = u & 0xffff0000u;
    f32x2 r; r.x = lo.f; r.y = hi.f;
    return r;
}
__device__ __forceinline__ u16 f2bf(float f) {   // RNE
    union { float f; u32 u; } v; v.f = f;
    u32 r = v.u + 0x7fffu + ((v.u >> 16) & 1u);
    return (u16)(r >> 16);
}
// packed f32->bf16 RNE (1 VALU for 2 elements)
__device__ __forceinline__ u32 cvtpk(float a, float b) {
    u32 r;
    asm("v_cvt_pk_bf16_f32 %0, %1, %2" : "=v"(r) : "v"(a), "v"(b));
    return r;
}
__device__ __forceinline__ int clampi(int v) {
    v = (v < 0) ? 0 : v;
    return (v >= N_NODES) ? (N_NODES - 1) : v;
}
// DPP row-rotate add: sums across each 16-lane row with zero LDS ops
template<int CTRL>
__device__ __forceinline__ float rradd(float v) {
    int t = __builtin_amdgcn_update_dpp(0, __float_as_int(v), CTRL, 0xF, 0xF, true);
    return v + __int_as_float(t);
}

__device__ __forceinline__ int ldidx(const void* ei, long long i, int m64) {
    int v = m64 ? (int)(((const long long*)ei)[i]) : ((const int*)ei)[i];
    return clampi(v);
}

// ---------- conversions ----------
__global__ void k_cvt_x(const float* __restrict__ x, u16* __restrict__ xb) {
    int i = blockIdx.x * 256 + threadIdx.x;
    float2 v = *(const float2*)(x + (size_t)i * 2);
    ((u32*)xb)[i] = cvtpk(v.x, v.y);
}

// W transpose/convert; block 0 additionally runs the int64-probe + bcnt zeroing
__global__ void k_cvt_w(const float* __restrict__ Wl, const float* __restrict__ Wr,
                        uint4* __restrict__ Wtg,
                        const int* __restrict__ ei32, int* __restrict__ flags,
                        int* __restrict__ bcnt) {
    __shared__ int cnt;
    if (blockIdx.x == 0) {
        int t = threadIdx.x;
        if (t == 0) cnt = 0;
        __syncthreads();
        if (ei32[2 * t + 1] == 0) atomicAdd(&cnt, 1);
        if (t < NBKT) bcnt[t] = 0;
        __syncthreads();
        if (t == 0) flags[0] = (cnt >= 255) ? 1 : 0;
    }
    int id = blockIdx.x * 256 + threadIdx.x;
    if (id >= N_LAYERS * 16 * 256) return;
    int l = id >> 12;
    int rem = id & 4095;
    int kc = rem >> 8;
    int n = rem & 255;
    const float* W = (n < 128) ? (Wl + (size_t)l * DIM * DIM + n)
                               : (Wr + (size_t)l * DIM * DIM + (n - 128));
    u16 c[8];
#pragma unroll
    for (int j = 0; j < 8; ++j) c[j] = f2bf(W[(size_t)(kc * 8 + j) * DIM]);
    uint4 o;
    o.x = (u32)c[0] | ((u32)c[1] << 16);
    o.y = (u32)c[2] | ((u32)c[3] << 16);
    o.z = (u32)c[4] | ((u32)c[5] << 16);
    o.w = (u32)c[6] | ((u32)c[7] << 16);
    Wtg[(size_t)l * 4096 + n * 16 + (kc ^ (n & 15))] = o;
}

// ---------- CSR build: LDS-staged bucket partition (196 blocks, 40 KB LDS) ----------
__global__ __launch_bounds__(1024) void k_part(
    const void* __restrict__ ei, const int* __restrict__ flags,
    int* __restrict__ bcnt, u32* __restrict__ bpk)
{
    __shared__ u32 ebuf[EPB];        // 32 KB
    __shared__ u8  bkb[EPB];         // 8 KB
    __shared__ int lh[NBKT];
    __shared__ int lb[NBKT + 1];
    __shared__ int gst[NBKT];
    __shared__ int sc[256];

    const int tid = threadIdx.x;
    const int m64 = flags[0];
    const long long e0 = (long long)blockIdx.x * EPB;

    for (int i = tid; i < NBKT; i += 1024) lh[i] = 0;
    __syncthreads();

    u32 pay[8];
    u32 meta[8];
    int nv = 0;
#pragma unroll
    for (int i = 0; i < 8; ++i) {
        long long e = e0 + i * 1024 + tid;
        if (e < N_EDGES) {
            int s = ldidx(ei, e, m64);
            int d = ldidx(ei, (long long)N_EDGES + e, m64);
            int b = d >> 8;
            int rank = atomicAdd(&lh[b], 1);
            pay[i] = (u32)s | ((u32)(d & 255) << 16);
            meta[i] = (u32)b | ((u32)rank << 8);
            nv = i + 1;
        }
    }
    __syncthreads();

    if (tid < 256) sc[tid] = (tid < NBKT) ? lh[tid] : 0;
    __syncthreads();
    for (int off = 1; off < 256; off <<= 1) {
        int v = 0;
        if (tid < 256 && tid >= off) v = sc[tid - off];
        __syncthreads();
        if (tid < 256) sc[tid] += v;
        __syncthreads();
    }
    if (tid < NBKT) lb[tid] = sc[tid] - lh[tid];
    if (tid == 0) lb[NBKT] = 0;
    if (tid < NBKT) gst[tid] = atomicAdd(&bcnt[tid], lh[tid]);
    __syncthreads();

#pragma unroll
    for (int i = 0; i < 8; ++i) {
        if (i < nv) {
            int b = (int)(meta[i] & 255);
            int rank = (int)(meta[i] >> 8);
            int p = lb[b] + rank;
            ebuf[p] = pay[i];
            bkb[p] = (u8)b;
        }
    }
    __syncthreads();

    int total = (e0 + EPB <= N_EDGES) ? EPB : (int)(N_EDGES - e0);
    for (int i = tid; i < total; i += 1024) {
        int b = (int)bkb[i];
        int off = gst[b] + (i - lb[b]);
        if (off < BCAP_A)
            bpk[(size_t)b * BCAP_A + off] = ebuf[i];
    }
}

// per-bucket degree + LOCAL row_off scan (PADDED to max(16, round4(deg+1)))
__global__ __launch_bounds__(256) void k_deg(
    const u32* __restrict__ bpk, const int* __restrict__ bcnt,
    const void* __restrict__ ei, const int* __restrict__ flags,
    int* __restrict__ row_off, int* __restrict__ btot)
{
    __shared__ int dh[256];
    __shared__ int sc[256];
    int b = blockIdx.x;
    int tid = threadIdx.x;
    dh[tid] = 0;
    __syncthreads();
    int cnt = bcnt[b];
    if (cnt <= BCAP_A) {
        for (int i = tid; i < cnt; i += 256)
            atomicAdd(&dh[(bpk[(size_t)b * BCAP_A + i] >> 16) & 255], 1);
    } else {
        int m64 = flags[0];
        for (long long e = tid; e < N_EDGES; e += 256) {
            int d = ldidx(ei, (long long)N_EDGES + e, m64);
            if ((d >> 8) == b) atomicAdd(&dh[d & 255], 1);
        }
    }
    __syncthreads();
    int d = b * 256 + tid;
    int v = 0;
    if (d < N_NODES) {
        v = (dh[tid] + 1 + 3) & ~3;      // +1 self loop, round up to mult of 4
        if (v < 16) v = 16;              // guarantee >=4 quads (prologue unconditional)
    }
    sc[tid] = v;
    __syncthreads();
    for (int off = 1; off < 256; off <<= 1) {
        int t = (tid >= off) ? sc[tid - off] : 0;
        __syncthreads();
        sc[tid] += t;
        __syncthreads();
    }
    if (d < N_NODES) row_off[d] = sc[tid] - v;    // local exclusive (padded)
    if (tid == 255) btot[b] = sc[255];
}

// scatter: col holds PRE-SCALED u32 byte offsets (src * 256)
// boff computed IN-KERNEL via LDS tree-reduce over btot (k_bscan folded in)
// NEW: per-row insertion sort by src (ascending) -> k_edge waves walk src in
// loose lockstep, shrinking the concurrent gather window to ~L2 size.
// Sum-of-exp aggregation is order-commutative, so this is math-neutral.
__global__ __launch_bounds__(256) void k_scat(
    const u32* __restrict__ bpk, const int* __restrict__ bcnt,
    int* __restrict__ row_off, const int* __restrict__ btot,
    u32* __restrict__ col,
    const void* __restrict__ ei, const int* __restrict__ flags)
{
    __shared__ u32 stage[SEGCAP];    // 48 KB
    __shared__ int cur[256];
    __shared__ int red[256];
    int b = blockIdx.x;
    int tid = threadIdx.x;

    // base0 = sum(btot[0..b-1])
    red[tid] = (tid < b) ? btot[tid] : 0;
    __syncthreads();
    for (int off = 128; off > 0; off >>= 1) {
        if (tid < off) red[tid] += red[tid + off];
        __syncthreads();
    }
    int base0 = red[0];

    int d_lo = b * 256;
    int d_hi = d_lo + 256; if (d_hi > N_NODES) d_hi = N_NODES;
    int seglen = btot[b];
    if (seglen > SEGCAP) seglen = SEGCAP;

    int d = d_lo + tid;
    int rloc = 0;
    int ext = 0;
    if (d < d_hi) {
        rloc = row_off[d];
        ext = (d + 1 < d_hi) ? row_off[d + 1] : btot[b];   // padded extent (local)
        if (ext > SEGCAP) ext = SEGCAP;
        if (rloc < SEGCAP) stage[rloc] = (u32)d * 256u;    // self loop first
        cur[tid] = rloc + 1;
    }
    __syncthreads();

    int cnt = bcnt[b];
    if (cnt <= BCAP_A) {
        for (int i = tid; i < cnt; i += 256) {
            u32 p = bpk[(size_t)b * BCAP_A + i];
            int pos = atomicAdd(&cur[(p >> 16) & 255], 1);
            if (pos < SEGCAP) stage[pos] = (p & 0xffffu) * 256u;
        }
    } else {
        int m64 = flags[0];
        for (long long e = tid; e < N_EDGES; e += 256) {
            int dd = ldidx(ei, (long long)N_EDGES + e, m64);
            if ((dd >> 8) == b) {
                int s = ldidx(ei, e, m64);
                int pos = atomicAdd(&cur[dd & 255], 1);
                if (pos < SEGCAP) stage[pos] = (u32)s * 256u;
            }
        }
    }
    __syncthreads();
    if (d < d_hi) {
        // fill pad slots with sentinel (contributes exactly 0 to softmax & aggregate)
        for (int i = cur[tid]; i < ext; ++i) stage[i] = (u32)SENT * 256u;
        // per-row insertion sort (ascending src); sentinels land at the end
        for (int i = rloc + 1; i < ext; ++i) {
            u32 key = stage[i];
            int j = i - 1;
            while (j >= rloc && stage[j] > key) { stage[j + 1] = stage[j]; --j; }
            stage[j + 1] = key;
        }
    }
    __syncthreads();
    for (int i = tid; i < seglen; i += 256)
        col[base0 + i] = stage[i];
    if (d < d_hi) row_off[d] = base0 + rloc;
    if (b == NBKT - 1 && tid == 0) row_off[N_NODES] = base0 + btot[b];
}

// ---------- MFMA GEMM: [xl|xr] = h_bf16 @ [Wl|Wr] + [bl|br]; both out bf16 ----------
// one 128-node tile per block (R8-proven); operand-swapped mfma(W, H);
// 2 node-tiles per wave so each LDS B-fragment read feeds TWO MFMAs.
// also writes the sentinel row xlb[SENT] = -1e4 * sign(att) (pad edges -> exp(e)=0)
__global__ __launch_bounds__(256) void k_mm(
    const u16* __restrict__ hb,
    const uint4* __restrict__ Wtg,
    const float* __restrict__ bl, const float* __restrict__ br,
    const float* __restrict__ att,
    u16* __restrict__ xlb,
    u16* __restrict__ xrb)
{
    __shared__ uint4 wsh[4096];          // 64 KB
    const int tid = threadIdx.x;
#pragma unroll
    for (int i = 0; i < 16; ++i) wsh[tid + i * 256] = Wtg[tid + i * 256];

    const int wave = tid >> 6, lane = tid & 63;
    const int q = lane >> 4, nn = lane & 15;
    const int mA0 = blockIdx.x * 128 + wave * 16 + nn;
    const int mA1 = mA0 + 64;

    FragU a0[4], a1[4];
    const uint4 az = make_uint4(0, 0, 0, 0);
#pragma unroll
    for (int s = 0; s < 4; ++s) {
        a0[s].u = (mA0 < N_NODES)
                ? *(const uint4*)(hb + (size_t)mA0 * DIM + s * 32 + q * 8) : az;
        a1[s].u = (mA1 < N_NODES)
                ? *(const uint4*)(hb + (size_t)mA1 * DIM + s * 32 + q * 8) : az;
    }
    __syncthreads();

    f32x4 acc0[16], acc1[16];
#pragma unroll
    for (int i = 0; i < 16; ++i) {
        acc0[i] = (f32x4){0.f, 0.f, 0.f, 0.f};
        acc1[i] = (f32x4){0.f, 0.f, 0.f, 0.f};
    }

#pragma unroll
    for (int s = 0; s < 4; ++s) {
#pragma unroll
        for (int nt = 0; nt < 16; ++nt) {
            int n = nt * 16 + nn;
            int kc = s * 4 + q;
            FragU b;
            b.u = wsh[n * 16 + (kc ^ (n & 15))];
            acc0[nt] = __builtin_amdgcn_mfma_f32_16x16x32_bf16(b.s, a0[s].s, acc0[nt], 0, 0, 0);
            acc1[nt] = __builtin_amdgcn_mfma_f32_16x16x32_bf16(b.s, a1[s].s, acc1[nt], 0, 0, 0);
        }
    }

    // D col = lane&15 -> node; D row = q*4 + r -> col within the 16-wide tile
    const bool v0 = (mA0 < N_NODES);
    const bool v1 = (mA1 < N_NODES);
#pragma unroll
    for (int nt = 0; nt < 16; ++nt) {
        int n0 = nt * 16 + q * 4;            // 4 consecutive output cols
        bool isL = (n0 < 128);
        const float* bp = isL ? (bl + n0) : (br + (n0 - 128));
        float4 bv = *(const float4*)bp;
        uint2 o0, o1;
        o0.x = cvtpk(acc0[nt][0] + bv.x, acc0[nt][1] + bv.y);
        o0.y = cvtpk(acc0[nt][2] + bv.z, acc0[nt][3] + bv.w);
        o1.x = cvtpk(acc1[nt][0] + bv.x, acc1[nt][1] + bv.y);
        o1.y = cvtpk(acc1[nt][2] + bv.z, acc1[nt][3] + bv.w);
        int nc = isL ? n0 : (n0 - 128);
        if (v0) {
            u16* dst = (isL ? xlb : xrb) + (size_t)mA0 * DIM + nc;
            *(uint2*)dst = o0;
        }
        if (v1) {
            u16* dst = (isL ? xlb : xrb) + (size_t)mA1 * DIM + nc;
            *(uint2*)dst = o1;
        }
    }

    if (blockIdx.x == 0 && tid < DIM) {
        float s = att[tid];
        xlb[(size_t)SENT * DIM + tid] = f2bf(s >= 0.f ? -10000.f : 10000.f);
    }
}

// ---------- fused edge phase: 1 node per 64-thread block, packed-f32 math ----------
#define PROC(U) do {                                                          \
    f32x2 x01 = bf2v((U).x), x23 = bf2v((U).y);                               \
    f32x2 x45 = bf2v((U).z), x67 = bf2v((U).w);                               \
    f32x2 z01 = x01 + xr01, z23 = x23 + xr23;                                 \
    f32x2 z45 = x45 + xr45, z67 = x67 + xr67;                                 \
    z01 = __builtin_elementwise_max(z01, z01 * negv);                         \
    z23 = __builtin_elementwise_max(z23, z23 * negv);                         \
    z45 = __builtin_elementwise_max(z45, z45 * negv);                         \
    z67 = __builtin_elementwise_max(z67, z67 * negv);                         \
    f32x2 pp2 = at01 * z01;                                                   \
    pp2 = at23 * z23 + pp2;                                                   \
    pp2 = at45 * z45 + pp2;                                                   \
    pp2 = at67 * z67 + pp2;                                                   \
    float pp = pp2.x + pp2.y;                                                 \
    pp = rradd<0x121>(pp);                                                    \
    pp = rradd<0x122>(pp);                                                    \
    pp = rradd<0x124>(pp);                                                    \
    pp = rradd<0x128>(pp);                                                    \
    float w_ = __builtin_amdgcn_exp2f(pp);                                    \
    lsum += w_;                                                               \
    f32x2 wv; wv.x = w_; wv.y = w_;                                           \
    ac01 = wv * x01 + ac01; ac23 = wv * x23 + ac23;                           \
    ac45 = wv * x45 + ac45; ac67 = wv * x67 + ac67;                           \
} while (0)

#define LDQ(U, Q) do {                                                        \
    u32 ob_ = __shfl(off, ((Q) << 2) + g, 64);                                \
    (U) = *(const uint4*)(xbp + (size_t)(ob_ + dofs));                        \
} while (0)

template <int RELU>
__global__ __launch_bounds__(64) void k_edge(
    const u16* __restrict__ xlb, const u16* __restrict__ xrb,
    const int* __restrict__ row_off, const u32* __restrict__ col,
    const float* __restrict__ att, const float* __restrict__ bias,
    u16* __restrict__ hout)
{
    const int node = blockIdx.x;
    const int lane = threadIdx.x & 63;
    const int g = lane >> 4;
    const int t = lane & 15;

    const int d0 = t * 8;
    const u32 dofs = (u32)(t << 4);
    const char* xbp = (const char*)xlb;

    uint4 xru = *(const uint4*)(xrb + (size_t)node * DIM + d0);
    f32x2 xr01 = bf2v(xru.x), xr23 = bf2v(xru.y), xr45 = bf2v(xru.z), xr67 = bf2v(xru.w);
    float2 a0 = *(const float2*)(att + d0);
    float2 a1 = *(const float2*)(att + d0 + 2);
    float2 a2 = *(const float2*)(att + d0 + 4);
    float2 a3 = *(const float2*)(att + d0 + 6);
    f32x2 at01, at23, at45, at67;
    at01.x = a0.x * LOG2E; at01.y = a0.y * LOG2E;
    at23.x = a1.x * LOG2E; at23.y = a1.y * LOG2E;
    at45.x = a2.x * LOG2E; at45.y = a2.y * LOG2E;
    at67.x = a3.x * LOG2E; at67.y = a3.y * LOG2E;
    f32x2 negv; negv.x = NEG; negv.y = NEG;

    const int beg = __builtin_amdgcn_readfirstlane(row_off[node]);
    const int end = __builtin_amdgcn_readfirstlane(row_off[node + 1]);
    const int n = end - beg;                 // padded: multiple of 4, >= 16
    const int nreg = (n < 64) ? n : 64;
    const int nq = nreg >> 2;                // >= 4 always

    u32 off = col[beg + lane];               // pre-scaled byte offsets

    f32x2 ac01, ac23, ac45, ac67;
    ac01.x = ac01.y = ac23.x = ac23.y = 0.f;
    ac45.x = ac45.y = ac67.x = ac67.y = 0.f;
    float lsum = 0.f;

    // prologue: 4 quads always valid -> unconditional prefetch
    uint4 u0, u1, u2, u3;
    LDQ(u0, 0); LDQ(u1, 1); LDQ(u2, 2); LDQ(u3, 3);

    // steady state: branch-free body, 4 loads always in flight
    int q = 0;
    for (; q + 8 <= nq; q += 4) {
        PROC(u0); LDQ(u0, q + 4);
        PROC(u1); LDQ(u1, q + 5);
        PROC(u2); LDQ(u2, q + 6);
        PROC(u3); LDQ(u3, q + 7);
    }
    // epilogue: 4..7 quads remain; wave-uniform scalar guards only
    PROC(u0); if (q + 4 < nq) LDQ(u0, q + 4);
    PROC(u1); if (q + 5 < nq) LDQ(u1, q + 5);
    PROC(u2); if (q + 6 < nq) LDQ(u2, q + 6);
    PROC(u3); if (q + 7 < nq) LDQ(u3, q + 7);
    q += 4;
    if (q     < nq) PROC(u0);
    if (q + 1 < nq) PROC(u1);
    if (q + 2 < nq) PROC(u2);

    // rare tail: rows longer than 64 (pads included; sentinel adds exactly 0)
    for (int j = beg + 64 + g; j < end; j += 4) {
        u32 ob_ = col[j];
        uint4 u = *(const uint4*)(xbp + (size_t)(ob_ + dofs));
        PROC(u);
    }

    // merge the 4 groups
    float accv[8] = {ac01.x, ac01.y, ac23.x, ac23.y, ac45.x, ac45.y, ac67.x, ac67.y};
#pragma unroll
    for (int i = 0; i < 8; ++i) {
        accv[i] += __shfl_xor(accv[i], 16, 64);
        accv[i] += __shfl_xor(accv[i], 32, 64);
    }
    lsum += __shfl_xor(lsum, 16, 64);
    lsum += __shfl_xor(lsum, 32, 64);

    if (g == 0) {
        float inv = 1.f / fmaxf(lsum, 1e-16f);
        float4 b0 = *(const float4*)(bias + d0);
        float4 b1 = *(const float4*)(bias + d0 + 4);
        float o0 = accv[0] * inv + b0.x;
        float o1 = accv[1] * inv + b0.y;
        float o2 = accv[2] * inv + b0.z;
        float o3 = accv[3] * inv + b0.w;
        float o4 = accv[4] * inv + b1.x;
        float o5 = accv[5] * inv + b1.y;
        float o6 = accv[6] * inv + b1.z;
        float o7 = accv[7] * inv + b1.w;
        if (RELU) {
            o0 = fmaxf(o0, 0.f); o1 = fmaxf(o1, 0.f);
            o2 = fmaxf(o2, 0.f); o3 = fmaxf(o3, 0.f);
            o4 = fmaxf(o4, 0.f); o5 = fmaxf(o5, 0.f);
            o6 = fmaxf(o6, 0.f); o7 = fmaxf(o7, 0.f);
        }
        uint4 o;
        o.x = cvtpk(o0, o1);
        o.y = cvtpk(o2, o3);
        o.z = cvtpk(o4, o5);
        o.w = cvtpk(o6, o7);
        *(uint4*)(hout + (size_t)node * DIM + d0) = o;
    }
}

// ---------- mean pool (bf16 h), vectorized uint4 loads ----------
__global__ __launch_bounds__(256) void k_mean_part(const u16* __restrict__ hb,
                                                   float* __restrict__ part) {
    __shared__ float sh[4][16][8];
    int t = threadIdx.x;
    int b = blockIdx.x;
    int c0 = (t & 15) * 8;
    int rl = t >> 4;
    int n0 = b * 400;
    float acc[8] = {0.f, 0.f, 0.f, 0.f, 0.f, 0.f, 0.f, 0.f};
    for (int i = 0; i < 25; ++i) {
        int r = n0 + rl + i * 16;
        uint4 v = *(const uint4*)(hb + (size_t)r * DIM + c0);
        f32x2 p0 = bf2v(v.x), p1 = bf2v(v.y), p2 = bf2v(v.z), p3 = bf2v(v.w);
        acc[0] += p0.x; acc[1] += p0.y;
        acc[2] += p1.x; acc[3] += p1.y;
        acc[4] += p2.x; acc[5] += p2.y;
        acc[6] += p3.x; acc[7] += p3.y;
    }
#pragma unroll
    for (int i = 0; i < 8; ++i) {
        acc[i] += __shfl_xor(acc[i], 16, 64);
        acc[i] += __shfl_xor(acc[i], 32, 64);
    }
    int wave = t >> 6;
    if ((t & 63) < 16) {
#pragma unroll
        for (int i = 0; i < 8; ++i) sh[wave][t & 15][i] = acc[i];
    }
    __syncthreads();
    if (t < 16) {
#pragma unroll
        for (int i = 0; i < 8; ++i) {
            float s = sh[0][t][i] + sh[1][t][i] + sh[2][t][i] + sh[3][t][i];
            part[b * DIM + t * 8 + i] = s;
        }
    }
}

__global__ void k_mean_final(const float* __restrict__ part, float* __restrict__ out) {
    int d = threadIdx.x;
    float s = 0.f;
    for (int b = 0; b < 125; ++b) s += part[b * DIM + d];
    out[d] = s * (1.f / (float)N_NODES);
}

// ---------- launch ----------
extern "C" void kernel_launch(void* const* d_in, const int* in_sizes, int n_in,
                              void* d_out, int out_size, void* d_ws, size_t ws_size,
                              hipStream_t stream) {
    int ix, iei, iWl, ibl, iWr, ibr, iatt, ibias;
    if (in_sizes[0] == N_NODES * DIM) {
        ix = 0; iei = 1; iWl = 2; ibl = 3; iWr = 4; ibr = 5; iatt = 6; ibias = 7;
    } else {
        iWl = 0; iWr = 1; iatt = 2; ibias = 3; ibl = 4; ibr = 5; iei = 6; ix = 7;
    }
    const float* x    = (const float*)d_in[ix];
    const void*  ei   = d_in[iei];
    const float* Wl   = (const float*)d_in[iWl];
    const float* bl   = (const float*)d_in[ibl];
    const float* Wr   = (const float*)d_in[iWr];
    const float* br   = (const float*)d_in[ibr];
    const float* att  = (const float*)d_in[iatt];
    const float* bias = (const float*)d_in[ibias];
    float* out = (float*)d_out;

    char* w = (char*)d_ws;
    float* part = (float*)w;      w += (size_t)256 * DIM * 4;
    uint4* Wtg = (uint4*)w;       w += (size_t)N_LAYERS * 4096 * 16;
    u16* xb  = (u16*)w;           w += (size_t)N_NODES * DIM * 2;
    u16* hb  = (u16*)w;           w += (size_t)N_NODES * DIM * 2;
    u16* xlb = (u16*)w;           w += (size_t)(N_NODES + 1) * DIM * 2;  // +1 sentinel row
    u16* xrb = (u16*)w;           w += (size_t)N_NODES * DIM * 2;
    int* row_off = (int*)w;       w += (size_t)(N_NODES + 4) * 4;
    int* flags = (int*)w;         w += 64;
    int* bcnt = (int*)w;          w += (size_t)(NBKT + 4) * 4;
    int* btot = (int*)w;          w += (size_t)(NBKT + 4) * 4;
    u32* bpk = (u32*)w;           w += (size_t)NBKT * BCAP_A * 4;
    u32* col = (u32*)w;           w += (size_t)(N_EDGES + 8 * N_NODES + 64) * 4;  // padded CSR, byte offsets

    k_cvt_x<<<(N_NODES * DIM / 2 + 255) / 256, 256, 0, stream>>>(x, xb);
    k_cvt_w<<<(N_LAYERS * 4096 + 255) / 256, 256, 0, stream>>>(Wl, Wr, Wtg,
                                                               (const int*)ei, flags, bcnt);
    k_part<<<PBLK, 1024, 0, stream>>>(ei, flags, bcnt, bpk);
    k_deg<<<NBKT, 256, 0, stream>>>(bpk, bcnt, ei, flags, row_off, btot);
    k_scat<<<NBKT, 256, 0, stream>>>(bpk, bcnt, row_off, btot, col, ei, flags);

    const int mm_grid = (N_NODES + 127) / 128;

    for (int layer = 0; layer < N_LAYERS; ++layer) {
        const uint4* Wp = Wtg + (size_t)layer * 4096;
        const float* blp = bl + (size_t)layer * DIM;
        const float* brp = br + (size_t)layer * DIM;
        const float* ap  = att + (size_t)layer * DIM;
        const float* bp  = bias + (size_t)layer * DIM;

        const u16* hin = (layer == 0) ? xb : hb;
        k_mm<<<mm_grid, 256, 0, stream>>>(hin, Wp, blp, brp, ap, xlb, xrb);

        if (layer < N_LAYERS - 1)
            k_edge<1><<<N_NODES, 64, 0, stream>>>(xlb, xrb, row_off, col, ap, bp, hb);
        else
            k_edge<0><<<N_NODES, 64, 0, stream>>>(xlb, xrb, row_off, col, ap, bp, hb);
    }

    k_mean_part<<<125, 256, 0, stream>>>(hb, part);
    k_mean_final<<<1, 128, 0, stream>>>(part, out);
}

// Round 13
// 498.472 us; speedup vs baseline: 1.1879x; 1.1879x over previous
//
#include <hip/hip_runtime.h>
#include <hip/hip_bf16.h>

#define N_NODES 50000
#define N_EDGES 1600000
#define DIM 128
#define N_LAYERS 5
#define NEG 0.2f

#define NBKT 196          // dst >> 8
#define BCAP_A 9472       // arena cap per bucket (mean 8163)
#define PBLK 196          // partition blocks (all CUs)
#define EPB 8192          // edges per partition block
#define SEGCAP 12288      // k_scat staging entries (u32)
#define SENT N_NODES      // sentinel src row for padded edges
#define LOG2E 1.4426950408889634f

typedef unsigned short u16;
typedef unsigned char u8;
typedef unsigned int u32;
using short8 = __attribute__((ext_vector_type(8))) short;
using f32x4  = __attribute__((ext_vector_type(4))) float;
typedef float f32x2 __attribute__((ext_vector_type(2)));

union FragU { uint4 u; short8 s; };

// ---------- helpers ----------
__device__ __forceinline__ f32x2 bf2v(u32 u) {
    union { u32 i; float f; } lo, hi;
    lo.i = u << 16;
    hi.i = u & 0xffff0000u;
    f32x2 r; r.x = lo.f; r.y = hi.f;
    return r;
}
__device__ __forceinline__ u16 f2bf(float f) {   // RNE
    union { float f; u32 u; } v; v.f = f;
    u32 r = v.u + 0x7fffu + ((v.u >> 16) & 1u);
    return (u16)(r >> 16);
}
// packed f32->bf16 RNE (1 VALU for 2 elements)
__device__ __forceinline__ u32 cvtpk(float a, float b) {
    u32 r;
    asm("v_cvt_pk_bf16_f32 %0, %1, %2" : "=v"(r) : "v"(a), "v"(b));
    return r;
}
__device__ __forceinline__ int clampi(int v) {
    v = (v < 0) ? 0 : v;
    return (v >= N_NODES) ? (N_NODES - 1) : v;
}
// DPP row-rotate add: sums across each 16-lane row with zero LDS ops
template<int CTRL>
__device__ __forceinline__ float rradd(float v) {
    int t = __builtin_amdgcn_update_dpp(0, __float_as_int(v), CTRL, 0xF, 0xF, true);
    return v + __int_as_float(t);
}

__device__ __forceinline__ int ldidx(const void* ei, long long i, int m64) {
    int v = m64 ? (int)(((const long long*)ei)[i]) : ((const int*)ei)[i];
    return clampi(v);
}

// ---------- conversions ----------
__global__ void k_cvt_x(const float* __restrict__ x, u16* __restrict__ xb) {
    int i = blockIdx.x * 256 + threadIdx.x;
    float2 v = *(const float2*)(x + (size_t)i * 2);
    ((u32*)xb)[i] = cvtpk(v.x, v.y);
}

// W transpose/convert; block 0 additionally runs the int64-probe + bcnt zeroing
__global__ void k_cvt_w(const float* __restrict__ Wl, const float* __restrict__ Wr,
                        uint4* __restrict__ Wtg,
                        const int* __restrict__ ei32, int* __restrict__ flags,
                        int* __restrict__ bcnt) {
    __shared__ int cnt;
    if (blockIdx.x == 0) {
        int t = threadIdx.x;
        if (t == 0) cnt = 0;
        __syncthreads();
        if (ei32[2 * t + 1] == 0) atomicAdd(&cnt, 1);
        if (t < NBKT) bcnt[t] = 0;
        __syncthreads();
        if (t == 0) flags[0] = (cnt >= 255) ? 1 : 0;
    }
    int id = blockIdx.x * 256 + threadIdx.x;
    if (id >= N_LAYERS * 16 * 256) return;
    int l = id >> 12;
    int rem = id & 4095;
    int kc = rem >> 8;
    int n = rem & 255;
    const float* W = (n < 128) ? (Wl + (size_t)l * DIM * DIM + n)
                               : (Wr + (size_t)l * DIM * DIM + (n - 128));
    u16 c[8];
#pragma unroll
    for (int j = 0; j < 8; ++j) c[j] = f2bf(W[(size_t)(kc * 8 + j) * DIM]);
    uint4 o;
    o.x = (u32)c[0] | ((u32)c[1] << 16);
    o.y = (u32)c[2] | ((u32)c[3] << 16);
    o.z = (u32)c[4] | ((u32)c[5] << 16);
    o.w = (u32)c[6] | ((u32)c[7] << 16);
    Wtg[(size_t)l * 4096 + n * 16 + (kc ^ (n & 15))] = o;
}

// ---------- CSR build: LDS-staged bucket partition (196 blocks, 40 KB LDS) ----------
__global__ __launch_bounds__(1024) void k_part(
    const void* __restrict__ ei, const int* __restrict__ flags,
    int* __restrict__ bcnt, u32* __restrict__ bpk)
{
    __shared__ u32 ebuf[EPB];        // 32 KB
    __shared__ u8  bkb[EPB];         // 8 KB
    __shared__ int lh[NBKT];
    __shared__ int lb[NBKT + 1];
    __shared__ int gst[NBKT];
    __shared__ int sc[256];

    const int tid = threadIdx.x;
    const int m64 = flags[0];
    const long long e0 = (long long)blockIdx.x * EPB;

    for (int i = tid; i < NBKT; i += 1024) lh[i] = 0;
    __syncthreads();

    u32 pay[8];
    u32 meta[8];
    int nv = 0;
#pragma unroll
    for (int i = 0; i < 8; ++i) {
        long long e = e0 + i * 1024 + tid;
        if (e < N_EDGES) {
            int s = ldidx(ei, e, m64);
            int d = ldidx(ei, (long long)N_EDGES + e, m64);
            int b = d >> 8;
            int rank = atomicAdd(&lh[b], 1);
            pay[i] = (u32)s | ((u32)(d & 255) << 16);
            meta[i] = (u32)b | ((u32)rank << 8);
            nv = i + 1;
        }
    }
    __syncthreads();

    if (tid < 256) sc[tid] = (tid < NBKT) ? lh[tid] : 0;
    __syncthreads();
    for (int off = 1; off < 256; off <<= 1) {
        int v = 0;
        if (tid < 256 && tid >= off) v = sc[tid - off];
        __syncthreads();
        if (tid < 256) sc[tid] += v;
        __syncthreads();
    }
    if (tid < NBKT) lb[tid] = sc[tid] - lh[tid];
    if (tid == 0) lb[NBKT] = 0;
    if (tid < NBKT) gst[tid] = atomicAdd(&bcnt[tid], lh[tid]);
    __syncthreads();

#pragma unroll
    for (int i = 0; i < 8; ++i) {
        if (i < nv) {
            int b = (int)(meta[i] & 255);
            int rank = (int)(meta[i] >> 8);
            int p = lb[b] + rank;
            ebuf[p] = pay[i];
            bkb[p] = (u8)b;
        }
    }
    __syncthreads();

    int total = (e0 + EPB <= N_EDGES) ? EPB : (int)(N_EDGES - e0);
    for (int i = tid; i < total; i += 1024) {
        int b = (int)bkb[i];
        int off = gst[b] + (i - lb[b]);
        if (off < BCAP_A)
            bpk[(size_t)b * BCAP_A + off] = ebuf[i];
    }
}

// per-bucket degree + LOCAL row_off scan (PADDED to max(16, round4(deg+1)))
__global__ __launch_bounds__(256) void k_deg(
    const u32* __restrict__ bpk, const int* __restrict__ bcnt,
    const void* __restrict__ ei, const int* __restrict__ flags,
    int* __restrict__ row_off, int* __restrict__ btot)
{
    __shared__ int dh[256];
    __shared__ int sc[256];
    int b = blockIdx.x;
    int tid = threadIdx.x;
    dh[tid] = 0;
    __syncthreads();
    int cnt = bcnt[b];
    if (cnt <= BCAP_A) {
        for (int i = tid; i < cnt; i += 256)
            atomicAdd(&dh[(bpk[(size_t)b * BCAP_A + i] >> 16) & 255], 1);
    } else {
        int m64 = flags[0];
        for (long long e = tid; e < N_EDGES; e += 256) {
            int d = ldidx(ei, (long long)N_EDGES + e, m64);
            if ((d >> 8) == b) atomicAdd(&dh[d & 255], 1);
        }
    }
    __syncthreads();
    int d = b * 256 + tid;
    int v = 0;
    if (d < N_NODES) {
        v = (dh[tid] + 1 + 3) & ~3;      // +1 self loop, round up to mult of 4
        if (v < 16) v = 16;              // guarantee >=4 quads (prologue unconditional)
    }
    sc[tid] = v;
    __syncthreads();
    for (int off = 1; off < 256; off <<= 1) {
        int t = (tid >= off) ? sc[tid - off] : 0;
        __syncthreads();
        sc[tid] += t;
        __syncthreads();
    }
    if (d < N_NODES) row_off[d] = sc[tid] - v;    // local exclusive (padded)
    if (tid == 255) btot[b] = sc[255];
}

// scatter: col holds PRE-SCALED u32 byte offsets (src * 256)
// boff computed IN-KERNEL via LDS tree-reduce over btot (k_bscan folded in)
// per-row COUNTING sort by coarse src bucket (src>>12, 16 buckets of 1 MB xl)
// -> k_edge waves walk src in loose lockstep; O(deg) per row, conflict-free
// counts layout cnt[b*256+tid] (bank = tid%32). Order-commutative -> math-neutral.
__global__ __launch_bounds__(256) void k_scat(
    const u32* __restrict__ bpk, const int* __restrict__ bcnt,
    int* __restrict__ row_off, const int* __restrict__ btot,
    u32* __restrict__ col,
    const void* __restrict__ ei, const int* __restrict__ flags)
{
    __shared__ u32 stage[SEGCAP];    // 48 KB
    __shared__ int cur[256];
    __shared__ int red[256];
    __shared__ int cntb[16 * 256];   // 16 KB: per-thread private bucket counts
    int b = blockIdx.x;
    int tid = threadIdx.x;

    // base0 = sum(btot[0..b-1])
    red[tid] = (tid < b) ? btot[tid] : 0;
    __syncthreads();
    for (int off = 128; off > 0; off >>= 1) {
        if (tid < off) red[tid] += red[tid + off];
        __syncthreads();
    }
    int base0 = red[0];

    int d_lo = b * 256;
    int d_hi = d_lo + 256; if (d_hi > N_NODES) d_hi = N_NODES;
    int seglen = btot[b];
    if (seglen > SEGCAP) seglen = SEGCAP;

    int d = d_lo + tid;
    int rloc = 0;
    int ext = 0;
    if (d < d_hi) {
        rloc = row_off[d];
        ext = (d + 1 < d_hi) ? row_off[d + 1] : btot[b];   // padded extent (local)
        if (ext > SEGCAP) ext = SEGCAP;
        if (rloc < SEGCAP) stage[rloc] = (u32)d * 256u;    // self loop
        cur[tid] = rloc + 1;
    }
    __syncthreads();

    int cnt = bcnt[b];
    if (cnt <= BCAP_A) {
        for (int i = tid; i < cnt; i += 256) {
            u32 p = bpk[(size_t)b * BCAP_A + i];
            int pos = atomicAdd(&cur[(p >> 16) & 255], 1);
            if (pos < SEGCAP) stage[pos] = (p & 0xffffu) * 256u;
        }
    } else {
        int m64 = flags[0];
        for (long long e = tid; e < N_EDGES; e += 256) {
            int dd = ldidx(ei, (long long)N_EDGES + e, m64);
            if ((dd >> 8) == b) {
                int s = ldidx(ei, e, m64);
                int pos = atomicAdd(&cur[dd & 255], 1);
                if (pos < SEGCAP) stage[pos] = (u32)s * 256u;
            }
        }
    }
    __syncthreads();
    if (d < d_hi) {
        // fill pad slots with sentinel (contributes exactly 0 to softmax & aggregate)
        for (int i = cur[tid]; i < ext; ++i) stage[i] = (u32)SENT * 256u;

        // ---- per-row counting sort by src>>12 (val>>20), O(len) ----
#pragma unroll
        for (int bb = 0; bb < 16; ++bb) cntb[bb * 256 + tid] = 0;
        for (int i = rloc; i < ext; ++i) {
            int bb = (int)(stage[i] >> 20);          // 0..12
            cntb[bb * 256 + tid] += 1;
        }
        int run = 0;
#pragma unroll
        for (int bb = 0; bb < 16; ++bb) {            // exclusive prefix, in place
            int c = cntb[bb * 256 + tid];
            cntb[bb * 256 + tid] = run;
            run += c;
        }
        int gbase = base0 + rloc;
        for (int i = rloc; i < ext; ++i) {
            u32 v = stage[i];
            int bb = (int)(v >> 20);
            int o = cntb[bb * 256 + tid];
            cntb[bb * 256 + tid] = o + 1;
            col[gbase + o] = v;                      // sorted row -> global
        }
        row_off[d] = base0 + rloc;
    }
    if (b == NBKT - 1 && tid == 0) row_off[N_NODES] = base0 + btot[b];
}

// ---------- MFMA GEMM: [xl|xr] = h_bf16 @ [Wl|Wr] + [bl|br]; both out bf16 ----------
// one 128-node tile per block (R8-proven); operand-swapped mfma(W, H);
// 2 node-tiles per wave so each LDS B-fragment read feeds TWO MFMAs.
// also writes the sentinel row xlb[SENT] = -1e4 * sign(att) (pad edges -> exp(e)=0)
__global__ __launch_bounds__(256) void k_mm(
    const u16* __restrict__ hb,
    const uint4* __restrict__ Wtg,
    const float* __restrict__ bl, const float* __restrict__ br,
    const float* __restrict__ att,
    u16* __restrict__ xlb,
    u16* __restrict__ xrb)
{
    __shared__ uint4 wsh[4096];          // 64 KB
    const int tid = threadIdx.x;
#pragma unroll
    for (int i = 0; i < 16; ++i) wsh[tid + i * 256] = Wtg[tid + i * 256];

    const int wave = tid >> 6, lane = tid & 63;
    const int q = lane >> 4, nn = lane & 15;
    const int mA0 = blockIdx.x * 128 + wave * 16 + nn;
    const int mA1 = mA0 + 64;

    FragU a0[4], a1[4];
    const uint4 az = make_uint4(0, 0, 0, 0);
#pragma unroll
    for (int s = 0; s < 4; ++s) {
        a0[s].u = (mA0 < N_NODES)
                ? *(const uint4*)(hb + (size_t)mA0 * DIM + s * 32 + q * 8) : az;
        a1[s].u = (mA1 < N_NODES)
                ? *(const uint4*)(hb + (size_t)mA1 * DIM + s * 32 + q * 8) : az;
    }
    __syncthreads();

    f32x4 acc0[16], acc1[16];
#pragma unroll
    for (int i = 0; i < 16; ++i) {
        acc0[i] = (f32x4){0.f, 0.f, 0.f, 0.f};
        acc1[i] = (f32x4){0.f, 0.f, 0.f, 0.f};
    }

#pragma unroll
    for (int s = 0; s < 4; ++s) {
#pragma unroll
        for (int nt = 0; nt < 16; ++nt) {
            int n = nt * 16 + nn;
            int kc = s * 4 + q;
            FragU b;
            b.u = wsh[n * 16 + (kc ^ (n & 15))];
            acc0[nt] = __builtin_amdgcn_mfma_f32_16x16x32_bf16(b.s, a0[s].s, acc0[nt], 0, 0, 0);
            acc1[nt] = __builtin_amdgcn_mfma_f32_16x16x32_bf16(b.s, a1[s].s, acc1[nt], 0, 0, 0);
        }
    }

    // D col = lane&15 -> node; D row = q*4 + r -> col within the 16-wide tile
    const bool v0 = (mA0 < N_NODES);
    const bool v1 = (mA1 < N_NODES);
#pragma unroll
    for (int nt = 0; nt < 16; ++nt) {
        int n0 = nt * 16 + q * 4;            // 4 consecutive output cols
        bool isL = (n0 < 128);
        const float* bp = isL ? (bl + n0) : (br + (n0 - 128));
        float4 bv = *(const float4*)bp;
        uint2 o0, o1;
        o0.x = cvtpk(acc0[nt][0] + bv.x, acc0[nt][1] + bv.y);
        o0.y = cvtpk(acc0[nt][2] + bv.z, acc0[nt][3] + bv.w);
        o1.x = cvtpk(acc1[nt][0] + bv.x, acc1[nt][1] + bv.y);
        o1.y = cvtpk(acc1[nt][2] + bv.z, acc1[nt][3] + bv.w);
        int nc = isL ? n0 : (n0 - 128);
        if (v0) {
            u16* dst = (isL ? xlb : xrb) + (size_t)mA0 * DIM + nc;
            *(uint2*)dst = o0;
        }
        if (v1) {
            u16* dst = (isL ? xlb : xrb) + (size_t)mA1 * DIM + nc;
            *(uint2*)dst = o1;
        }
    }

    if (blockIdx.x == 0 && tid < DIM) {
        float s = att[tid];
        xlb[(size_t)SENT * DIM + tid] = f2bf(s >= 0.f ? -10000.f : 10000.f);
    }
}

// ---------- fused edge phase: 1 node per 64-thread block, packed-f32 math ----------
#define PROC(U) do {                                                          \
    f32x2 x01 = bf2v((U).x), x23 = bf2v((U).y);                               \
    f32x2 x45 = bf2v((U).z), x67 = bf2v((U).w);                               \
    f32x2 z01 = x01 + xr01, z23 = x23 + xr23;                                 \
    f32x2 z45 = x45 + xr45, z67 = x67 + xr67;                                 \
    z01 = __builtin_elementwise_max(z01, z01 * negv);                         \
    z23 = __builtin_elementwise_max(z23, z23 * negv);                         \
    z45 = __builtin_elementwise_max(z45, z45 * negv);                         \
    z67 = __builtin_elementwise_max(z67, z67 * negv);                         \
    f32x2 pp2 = at01 * z01;                                                   \
    pp2 = at23 * z23 + pp2;                                                   \
    pp2 = at45 * z45 + pp2;                                                   \
    pp2 = at67 * z67 + pp2;                                                   \
    float pp = pp2.x + pp2.y;                                                 \
    pp = rradd<0x121>(pp);                                                    \
    pp = rradd<0x122>(pp);                                                    \
    pp = rradd<0x124>(pp);                                                    \
    pp = rradd<0x128>(pp);                                                    \
    float w_ = __builtin_amdgcn_exp2f(pp);                                    \
    lsum += w_;                                                               \
    f32x2 wv; wv.x = w_; wv.y = w_;                                           \
    ac01 = wv * x01 + ac01; ac23 = wv * x23 + ac23;                           \
    ac45 = wv * x45 + ac45; ac67 = wv * x67 + ac67;                           \
} while (0)

#define LDQ(U, Q) do {                                                        \
    u32 ob_ = __shfl(off, ((Q) << 2) + g, 64);                                \
    (U) = *(const uint4*)(xbp + (size_t)(ob_ + dofs));                        \
} while (0)

template <int RELU>
__global__ __launch_bounds__(64) void k_edge(
    const u16* __restrict__ xlb, const u16* __restrict__ xrb,
    const int* __restrict__ row_off, const u32* __restrict__ col,
    const float* __restrict__ att, const float* __restrict__ bias,
    u16* __restrict__ hout)
{
    const int node = blockIdx.x;
    const int lane = threadIdx.x & 63;
    const int g = lane >> 4;
    const int t = lane & 15;

    const int d0 = t * 8;
    const u32 dofs = (u32)(t << 4);
    const char* xbp = (const char*)xlb;

    uint4 xru = *(const uint4*)(xrb + (size_t)node * DIM + d0);
    f32x2 xr01 = bf2v(xru.x), xr23 = bf2v(xru.y), xr45 = bf2v(xru.z), xr67 = bf2v(xru.w);
    float2 a0 = *(const float2*)(att + d0);
    float2 a1 = *(const float2*)(att + d0 + 2);
    float2 a2 = *(const float2*)(att + d0 + 4);
    float2 a3 = *(const float2*)(att + d0 + 6);
    f32x2 at01, at23, at45, at67;
    at01.x = a0.x * LOG2E; at01.y = a0.y * LOG2E;
    at23.x = a1.x * LOG2E; at23.y = a1.y * LOG2E;
    at45.x = a2.x * LOG2E; at45.y = a2.y * LOG2E;
    at67.x = a3.x * LOG2E; at67.y = a3.y * LOG2E;
    f32x2 negv; negv.x = NEG; negv.y = NEG;

    const int beg = __builtin_amdgcn_readfirstlane(row_off[node]);
    const int end = __builtin_amdgcn_readfirstlane(row_off[node + 1]);
    const int n = end - beg;                 // padded: multiple of 4, >= 16
    const int nreg = (n < 64) ? n : 64;
    const int nq = nreg >> 2;                // >= 4 always

    u32 off = col[beg + lane];               // pre-scaled byte offsets

    f32x2 ac01, ac23, ac45, ac67;
    ac01.x = ac01.y = ac23.x = ac23.y = 0.f;
    ac45.x = ac45.y = ac67.x = ac67.y = 0.f;
    float lsum = 0.f;

    // prologue: 4 quads always valid -> unconditional prefetch
    uint4 u0, u1, u2, u3;
    LDQ(u0, 0); LDQ(u1, 1); LDQ(u2, 2); LDQ(u3, 3);

    // steady state: branch-free body, 4 loads always in flight
    int q = 0;
    for (; q + 8 <= nq; q += 4) {
        PROC(u0); LDQ(u0, q + 4);
        PROC(u1); LDQ(u1, q + 5);
        PROC(u2); LDQ(u2, q + 6);
        PROC(u3); LDQ(u3, q + 7);
    }
    // epilogue: 4..7 quads remain; wave-uniform scalar guards only
    PROC(u0); if (q + 4 < nq) LDQ(u0, q + 4);
    PROC(u1); if (q + 5 < nq) LDQ(u1, q + 5);
    PROC(u2); if (q + 6 < nq) LDQ(u2, q + 6);
    PROC(u3); if (q + 7 < nq) LDQ(u3, q + 7);
    q += 4;
    if (q     < nq) PROC(u0);
    if (q + 1 < nq) PROC(u1);
    if (q + 2 < nq) PROC(u2);

    // rare tail: rows longer than 64 (pads included; sentinel adds exactly 0)
    for (int j = beg + 64 + g; j < end; j += 4) {
        u32 ob_ = col[j];
        uint4 u = *(const uint4*)(xbp + (size_t)(ob_ + dofs));
        PROC(u);
    }

    // merge the 4 groups
    float accv[8] = {ac01.x, ac01.y, ac23.x, ac23.y, ac45.x, ac45.y, ac67.x, ac67.y};
#pragma unroll
    for (int i = 0; i < 8; ++i) {
        accv[i] += __shfl_xor(accv[i], 16, 64);
        accv[i] += __shfl_xor(accv[i], 32, 64);
    }
    lsum += __shfl_xor(lsum, 16, 64);
    lsum += __shfl_xor(lsum, 32, 64);

    if (g == 0) {
        float inv = 1.f / fmaxf(lsum, 1e-16f);
        float4 b0 = *(const float4*)(bias + d0);
        float4 b1 = *(const float4*)(bias + d0 + 4);
        float o0 = accv[0] * inv + b0.x;
        float o1 = accv[1] * inv + b0.y;
        float o2 = accv[2] * inv + b0.z;
        float o3 = accv[3] * inv + b0.w;
        float o4 = accv[4] * inv + b1.x;
        float o5 = accv[5] * inv + b1.y;
        float o6 = accv[6] * inv + b1.z;
        float o7 = accv[7] * inv + b1.w;
        if (RELU) {
            o0 = fmaxf(o0, 0.f); o1 = fmaxf(o1, 0.f);
            o2 = fmaxf(o2, 0.f); o3 = fmaxf(o3, 0.f);
            o4 = fmaxf(o4, 0.f); o5 = fmaxf(o5, 0.f);
            o6 = fmaxf(o6, 0.f); o7 = fmaxf(o7, 0.f);
        }
        uint4 o;
        o.x = cvtpk(o0, o1);
        o.y = cvtpk(o2, o3);
        o.z = cvtpk(o4, o5);
        o.w = cvtpk(o6, o7);
        *(uint4*)(hout + (size_t)node * DIM + d0) = o;
    }
}

// ---------- mean pool (bf16 h), vectorized uint4 loads ----------
__global__ __launch_bounds__(256) void k_mean_part(const u16* __restrict__ hb,
                                                   float* __restrict__ part) {
    __shared__ float sh[4][16][8];
    int t = threadIdx.x;
    int b = blockIdx.x;
    int c0 = (t & 15) * 8;
    int rl = t >> 4;
    int n0 = b * 400;
    float acc[8] = {0.f, 0.f, 0.f, 0.f, 0.f, 0.f, 0.f, 0.f};
    for (int i = 0; i < 25; ++i) {
        int r = n0 + rl + i * 16;
        uint4 v = *(const uint4*)(hb + (size_t)r * DIM + c0);
        f32x2 p0 = bf2v(v.x), p1 = bf2v(v.y), p2 = bf2v(v.z), p3 = bf2v(v.w);
        acc[0] += p0.x; acc[1] += p0.y;
        acc[2] += p1.x; acc[3] += p1.y;
        acc[4] += p2.x; acc[5] += p2.y;
        acc[6] += p3.x; acc[7] += p3.y;
    }
#pragma unroll
    for (int i = 0; i < 8; ++i) {
        acc[i] += __shfl_xor(acc[i], 16, 64);
        acc[i] += __shfl_xor(acc[i], 32, 64);
    }
    int wave = t >> 6;
    if ((t & 63) < 16) {
#pragma unroll
        for (int i = 0; i < 8; ++i) sh[wave][t & 15][i] = acc[i];
    }
    __syncthreads();
    if (t < 16) {
#pragma unroll
        for (int i = 0; i < 8; ++i) {
            float s = sh[0][t][i] + sh[1][t][i] + sh[2][t][i] + sh[3][t][i];
            part[b * DIM + t * 8 + i] = s;
        }
    }
}

__global__ void k_mean_final(const float* __restrict__ part, float* __restrict__ out) {
    int d = threadIdx.x;
    float s = 0.f;
    for (int b = 0; b < 125; ++b) s += part[b * DIM + d];
    out[d] = s * (1.f / (float)N_NODES);
}

// ---------- launch ----------
extern "C" void kernel_launch(void* const* d_in, const int* in_sizes, int n_in,
                              void* d_out, int out_size, void* d_ws, size_t ws_size,
                              hipStream_t stream) {
    int ix, iei, iWl, ibl, iWr, ibr, iatt, ibias;
    if (in_sizes[0] == N_NODES * DIM) {
        ix = 0; iei = 1; iWl = 2; ibl = 3; iWr = 4; ibr = 5; iatt = 6; ibias = 7;
    } else {
        iWl = 0; iWr = 1; iatt = 2; ibias = 3; ibl = 4; ibr = 5; iei = 6; ix = 7;
    }
    const float* x    = (const float*)d_in[ix];
    const void*  ei   = d_in[iei];
    const float* Wl   = (const float*)d_in[iWl];
    const float* bl   = (const float*)d_in[ibl];
    const float* Wr   = (const float*)d_in[iWr];
    const float* br   = (const float*)d_in[ibr];
    const float* att  = (const float*)d_in[iatt];
    const float* bias = (const float*)d_in[ibias];
    float* out = (float*)d_out;

    char* w = (char*)d_ws;
    float* part = (float*)w;      w += (size_t)256 * DIM * 4;
    uint4* Wtg = (uint4*)w;       w += (size_t)N_LAYERS * 4096 * 16;
    u16* xb  = (u16*)w;           w += (size_t)N_NODES * DIM * 2;
    u16* hb  = (u16*)w;           w += (size_t)N_NODES * DIM * 2;
    u16* xlb = (u16*)w;           w += (size_t)(N_NODES + 1) * DIM * 2;  // +1 sentinel row
    u16* xrb = (u16*)w;           w += (size_t)N_NODES * DIM * 2;
    int* row_off = (int*)w;       w += (size_t)(N_NODES + 4) * 4;
    int* flags = (int*)w;         w += 64;
    int* bcnt = (int*)w;          w += (size_t)(NBKT + 4) * 4;
    int* btot = (int*)w;          w += (size_t)(NBKT + 4) * 4;
    u32* bpk = (u32*)w;           w += (size_t)NBKT * BCAP_A * 4;
    u32* col = (u32*)w;           w += (size_t)(N_EDGES + 8 * N_NODES + 64) * 4;  // padded CSR, byte offsets

    k_cvt_x<<<(N_NODES * DIM / 2 + 255) / 256, 256, 0, stream>>>(x, xb);
    k_cvt_w<<<(N_LAYERS * 4096 + 255) / 256, 256, 0, stream>>>(Wl, Wr, Wtg,
                                                               (const int*)ei, flags, bcnt);
    k_part<<<PBLK, 1024, 0, stream>>>(ei, flags, bcnt, bpk);
    k_deg<<<NBKT, 256, 0, stream>>>(bpk, bcnt, ei, flags, row_off, btot);
    k_scat<<<NBKT, 256, 0, stream>>>(bpk, bcnt, row_off, btot, col, ei, flags);

    const int mm_grid = (N_NODES + 127) / 128;

    for (int layer = 0; layer < N_LAYERS; ++layer) {
        const uint4* Wp = Wtg + (size_t)layer * 4096;
        const float* blp = bl + (size_t)layer * DIM;
        const float* brp = br + (size_t)layer * DIM;
        const float* ap  = att + (size_t)layer * DIM;
        const float* bp  = bias + (size_t)layer * DIM;

        const u16* hin = (layer == 0) ? xb : hb;
        k_mm<<<mm_grid, 256, 0, stream>>>(hin, Wp, blp, brp, ap, xlb, xrb);

        if (layer < N_LAYERS - 1)
            k_edge<1><<<N_NODES, 64, 0, stream>>>(xlb, xrb, row_off, col, ap, bp, hb);
        else
            k_edge<0><<<N_NODES, 64, 0, stream>>>(xlb, xrb, row_off, col, ap, bp, hb);
    }

    k_mean_part<<<125, 256, 0, stream>>>(hb, part);
    k_mean_final<<<1, 128, 0, stream>>>(part, out);
}

// Round 14
// 483.972 us; speedup vs baseline: 1.2234x; 1.0300x over previous
//
#include <hip/hip_runtime.h>
#include <hip/hip_bf16.h>

#define N_NODES 50000
#define N_EDGES 1600000
#define DIM 128
#define N_LAYERS 5
#define NEG 0.2f

#define NBKT 196          // dst >> 8
#define BCAP_A 9472       // arena cap per bucket (mean 8163)
#define PBLK 196          // partition blocks (all CUs)
#define EPB 8192          // edges per partition block
#define SEGCAP 12288      // k_scat staging entries (u32)
#define SENT N_NODES      // sentinel src row for padded edges
#define LOG2E 1.4426950408889634f

typedef unsigned short u16;
typedef unsigned char u8;
typedef unsigned int u32;
using short8 = __attribute__((ext_vector_type(8))) short;
using f32x4  = __attribute__((ext_vector_type(4))) float;
typedef float f32x2 __attribute__((ext_vector_type(2)));

union FragU { uint4 u; short8 s; };

// ---------- helpers ----------
__device__ __forceinline__ f32x2 bf2v(u32 u) {
    union { u32 i; float f; } lo, hi;
    lo.i = u << 16;
    hi.i = u & 0xffff0000u;
    f32x2 r; r.x = lo.f; r.y = hi.f;
    return r;
}
__device__ __forceinline__ u16 f2bf(float f) {   // RNE
    union { float f; u32 u; } v; v.f = f;
    u32 r = v.u + 0x7fffu + ((v.u >> 16) & 1u);
    return (u16)(r >> 16);
}
// packed f32->bf16 RNE (1 VALU for 2 elements)
__device__ __forceinline__ u32 cvtpk(float a, float b) {
    u32 r;
    asm("v_cvt_pk_bf16_f32 %0, %1, %2" : "=v"(r) : "v"(a), "v"(b));
    return r;
}
__device__ __forceinline__ int clampi(int v) {
    v = (v < 0) ? 0 : v;
    return (v >= N_NODES) ? (N_NODES - 1) : v;
}
// DPP row-rotate add: sums across each 16-lane row with zero LDS ops
template<int CTRL>
__device__ __forceinline__ float rradd(float v) {
    int t = __builtin_amdgcn_update_dpp(0, __float_as_int(v), CTRL, 0xF, 0xF, true);
    return v + __int_as_float(t);
}

__device__ __forceinline__ int ldidx(const void* ei, long long i, int m64) {
    int v = m64 ? (int)(((const long long*)ei)[i]) : ((const int*)ei)[i];
    return clampi(v);
}

// ---------- conversions ----------
__global__ void k_cvt_x(const float* __restrict__ x, u16* __restrict__ xb) {
    int i = blockIdx.x * 256 + threadIdx.x;
    float2 v = *(const float2*)(x + (size_t)i * 2);
    ((u32*)xb)[i] = cvtpk(v.x, v.y);
}

// W transpose/convert; block 0 additionally runs the int64-probe + bcnt zeroing
__global__ void k_cvt_w(const float* __restrict__ Wl, const float* __restrict__ Wr,
                        uint4* __restrict__ Wtg,
                        const int* __restrict__ ei32, int* __restrict__ flags,
                        int* __restrict__ bcnt) {
    __shared__ int cnt;
    if (blockIdx.x == 0) {
        int t = threadIdx.x;
        if (t == 0) cnt = 0;
        __syncthreads();
        if (ei32[2 * t + 1] == 0) atomicAdd(&cnt, 1);
        if (t < NBKT) bcnt[t] = 0;
        __syncthreads();
        if (t == 0) flags[0] = (cnt >= 255) ? 1 : 0;
    }
    int id = blockIdx.x * 256 + threadIdx.x;
    if (id >= N_LAYERS * 16 * 256) return;
    int l = id >> 12;
    int rem = id & 4095;
    int kc = rem >> 8;
    int n = rem & 255;
    const float* W = (n < 128) ? (Wl + (size_t)l * DIM * DIM + n)
                               : (Wr + (size_t)l * DIM * DIM + (n - 128));
    u16 c[8];
#pragma unroll
    for (int j = 0; j < 8; ++j) c[j] = f2bf(W[(size_t)(kc * 8 + j) * DIM]);
    uint4 o;
    o.x = (u32)c[0] | ((u32)c[1] << 16);
    o.y = (u32)c[2] | ((u32)c[3] << 16);
    o.z = (u32)c[4] | ((u32)c[5] << 16);
    o.w = (u32)c[6] | ((u32)c[7] << 16);
    Wtg[(size_t)l * 4096 + n * 16 + (kc ^ (n & 15))] = o;
}

// ---------- CSR build: LDS-staged bucket partition (196 blocks, 40 KB LDS) ----------
__global__ __launch_bounds__(1024) void k_part(
    const void* __restrict__ ei, const int* __restrict__ flags,
    int* __restrict__ bcnt, u32* __restrict__ bpk)
{
    __shared__ u32 ebuf[EPB];        // 32 KB
    __shared__ u8  bkb[EPB];         // 8 KB
    __shared__ int lh[NBKT];
    __shared__ int lb[NBKT + 1];
    __shared__ int gst[NBKT];
    __shared__ int sc[256];

    const int tid = threadIdx.x;
    const int m64 = flags[0];
    const long long e0 = (long long)blockIdx.x * EPB;

    for (int i = tid; i < NBKT; i += 1024) lh[i] = 0;
    __syncthreads();

    u32 pay[8];
    u32 meta[8];
    int nv = 0;
#pragma unroll
    for (int i = 0; i < 8; ++i) {
        long long e = e0 + i * 1024 + tid;
        if (e < N_EDGES) {
            int s = ldidx(ei, e, m64);
            int d = ldidx(ei, (long long)N_EDGES + e, m64);
            int b = d >> 8;
            int rank = atomicAdd(&lh[b], 1);
            pay[i] = (u32)s | ((u32)(d & 255) << 16);
            meta[i] = (u32)b | ((u32)rank << 8);
            nv = i + 1;
        }
    }
    __syncthreads();

    if (tid < 256) sc[tid] = (tid < NBKT) ? lh[tid] : 0;
    __syncthreads();
    for (int off = 1; off < 256; off <<= 1) {
        int v = 0;
        if (tid < 256 && tid >= off) v = sc[tid - off];
        __syncthreads();
        if (tid < 256) sc[tid] += v;
        __syncthreads();
    }
    if (tid < NBKT) lb[tid] = sc[tid] - lh[tid];
    if (tid == 0) lb[NBKT] = 0;
    if (tid < NBKT) gst[tid] = atomicAdd(&bcnt[tid], lh[tid]);
    __syncthreads();

#pragma unroll
    for (int i = 0; i < 8; ++i) {
        if (i < nv) {
            int b = (int)(meta[i] & 255);
            int rank = (int)(meta[i] >> 8);
            int p = lb[b] + rank;
            ebuf[p] = pay[i];
            bkb[p] = (u8)b;
        }
    }
    __syncthreads();

    int total = (e0 + EPB <= N_EDGES) ? EPB : (int)(N_EDGES - e0);
    for (int i = tid; i < total; i += 1024) {
        int b = (int)bkb[i];
        int off = gst[b] + (i - lb[b]);
        if (off < BCAP_A)
            bpk[(size_t)b * BCAP_A + off] = ebuf[i];
    }
}

// per-bucket degree + LOCAL row_off scan (PADDED to max(16, round4(deg+1)))
__global__ __launch_bounds__(256) void k_deg(
    const u32* __restrict__ bpk, const int* __restrict__ bcnt,
    const void* __restrict__ ei, const int* __restrict__ flags,
    int* __restrict__ row_off, int* __restrict__ btot)
{
    __shared__ int dh[256];
    __shared__ int sc[256];
    int b = blockIdx.x;
    int tid = threadIdx.x;
    dh[tid] = 0;
    __syncthreads();
    int cnt = bcnt[b];
    if (cnt <= BCAP_A) {
        for (int i = tid; i < cnt; i += 256)
            atomicAdd(&dh[(bpk[(size_t)b * BCAP_A + i] >> 16) & 255], 1);
    } else {
        int m64 = flags[0];
        for (long long e = tid; e < N_EDGES; e += 256) {
            int d = ldidx(ei, (long long)N_EDGES + e, m64);
            if ((d >> 8) == b) atomicAdd(&dh[d & 255], 1);
        }
    }
    __syncthreads();
    int d = b * 256 + tid;
    int v = 0;
    if (d < N_NODES) {
        v = (dh[tid] + 1 + 3) & ~3;      // +1 self loop, round up to mult of 4
        if (v < 16) v = 16;              // guarantee >=4 quads (prologue unconditional)
    }
    sc[tid] = v;
    __syncthreads();
    for (int off = 1; off < 256; off <<= 1) {
        int t = (tid >= off) ? sc[tid - off] : 0;
        __syncthreads();
        sc[tid] += t;
        __syncthreads();
    }
    if (d < N_NODES) row_off[d] = sc[tid] - v;    // local exclusive (padded)
    if (tid == 255) btot[b] = sc[255];
}

// scatter: col holds PRE-SCALED u32 byte offsets (src * 256)
// boff computed IN-KERNEL via LDS tree-reduce over btot (k_bscan folded in)
__global__ __launch_bounds__(256) void k_scat(
    const u32* __restrict__ bpk, const int* __restrict__ bcnt,
    int* __restrict__ row_off, const int* __restrict__ btot,
    u32* __restrict__ col,
    const void* __restrict__ ei, const int* __restrict__ flags)
{
    __shared__ u32 stage[SEGCAP];    // 48 KB
    __shared__ int cur[256];
    __shared__ int red[256];
    int b = blockIdx.x;
    int tid = threadIdx.x;

    // base0 = sum(btot[0..b-1])
    red[tid] = (tid < b) ? btot[tid] : 0;
    __syncthreads();
    for (int off = 128; off > 0; off >>= 1) {
        if (tid < off) red[tid] += red[tid + off];
        __syncthreads();
    }
    int base0 = red[0];

    int d_lo = b * 256;
    int d_hi = d_lo + 256; if (d_hi > N_NODES) d_hi = N_NODES;
    int seglen = btot[b];
    if (seglen > SEGCAP) seglen = SEGCAP;

    int d = d_lo + tid;
    int rloc = 0;
    int ext = 0;
    if (d < d_hi) {
        rloc = row_off[d];
        ext = (d + 1 < d_hi) ? row_off[d + 1] : btot[b];   // padded extent (local)
        if (ext > SEGCAP) ext = SEGCAP;
        if (rloc < SEGCAP) stage[rloc] = (u32)d * 256u;    // self loop first
        cur[tid] = rloc + 1;
    }
    __syncthreads();

    int cnt = bcnt[b];
    if (cnt <= BCAP_A) {
        for (int i = tid; i < cnt; i += 256) {
            u32 p = bpk[(size_t)b * BCAP_A + i];
            int pos = atomicAdd(&cur[(p >> 16) & 255], 1);
            if (pos < SEGCAP) stage[pos] = (p & 0xffffu) * 256u;
        }
    } else {
        int m64 = flags[0];
        for (long long e = tid; e < N_EDGES; e += 256) {
            int dd = ldidx(ei, (long long)N_EDGES + e, m64);
            if ((dd >> 8) == b) {
                int s = ldidx(ei, e, m64);
                int pos = atomicAdd(&cur[dd & 255], 1);
                if (pos < SEGCAP) stage[pos] = (u32)s * 256u;
            }
        }
    }
    __syncthreads();
    // fill pad slots with sentinel (contributes exactly 0 to softmax & aggregate)
    if (d < d_hi) {
        for (int i = cur[tid]; i < ext; ++i) stage[i] = (u32)SENT * 256u;
    }
    __syncthreads();
    for (int i = tid; i < seglen; i += 256)
        col[base0 + i] = stage[i];
    if (d < d_hi) row_off[d] = base0 + rloc;
    if (b == NBKT - 1 && tid == 0) row_off[N_NODES] = base0 + btot[b];
}

// ---------- MFMA GEMM: [xl|xr] = h_bf16 @ [Wl|Wr] + [bl|br]; both out bf16 ----------
// one 128-node tile per block (R8-proven); operand-swapped mfma(W, H);
// 2 node-tiles per wave so each LDS B-fragment read feeds TWO MFMAs.
// also writes the sentinel row xlb[SENT] = -1e4 * sign(att) (pad edges -> exp(e)=0)
__global__ __launch_bounds__(256) void k_mm(
    const u16* __restrict__ hb,
    const uint4* __restrict__ Wtg,
    const float* __restrict__ bl, const float* __restrict__ br,
    const float* __restrict__ att,
    u16* __restrict__ xlb,
    u16* __restrict__ xrb)
{
    __shared__ uint4 wsh[4096];          // 64 KB
    const int tid = threadIdx.x;
#pragma unroll
    for (int i = 0; i < 16; ++i) wsh[tid + i * 256] = Wtg[tid + i * 256];

    const int wave = tid >> 6, lane = tid & 63;
    const int q = lane >> 4, nn = lane & 15;
    const int mA0 = blockIdx.x * 128 + wave * 16 + nn;
    const int mA1 = mA0 + 64;

    FragU a0[4], a1[4];
    const uint4 az = make_uint4(0, 0, 0, 0);
#pragma unroll
    for (int s = 0; s < 4; ++s) {
        a0[s].u = (mA0 < N_NODES)
                ? *(const uint4*)(hb + (size_t)mA0 * DIM + s * 32 + q * 8) : az;
        a1[s].u = (mA1 < N_NODES)
                ? *(const uint4*)(hb + (size_t)mA1 * DIM + s * 32 + q * 8) : az;
    }
    __syncthreads();

    f32x4 acc0[16], acc1[16];
#pragma unroll
    for (int i = 0; i < 16; ++i) {
        acc0[i] = (f32x4){0.f, 0.f, 0.f, 0.f};
        acc1[i] = (f32x4){0.f, 0.f, 0.f, 0.f};
    }

#pragma unroll
    for (int s = 0; s < 4; ++s) {
#pragma unroll
        for (int nt = 0; nt < 16; ++nt) {
            int n = nt * 16 + nn;
            int kc = s * 4 + q;
            FragU b;
            b.u = wsh[n * 16 + (kc ^ (n & 15))];
            acc0[nt] = __builtin_amdgcn_mfma_f32_16x16x32_bf16(b.s, a0[s].s, acc0[nt], 0, 0, 0);
            acc1[nt] = __builtin_amdgcn_mfma_f32_16x16x32_bf16(b.s, a1[s].s, acc1[nt], 0, 0, 0);
        }
    }

    // D col = lane&15 -> node; D row = q*4 + r -> col within the 16-wide tile
    const bool v0 = (mA0 < N_NODES);
    const bool v1 = (mA1 < N_NODES);
#pragma unroll
    for (int nt = 0; nt < 16; ++nt) {
        int n0 = nt * 16 + q * 4;            // 4 consecutive output cols
        bool isL = (n0 < 128);
        const float* bp = isL ? (bl + n0) : (br + (n0 - 128));
        float4 bv = *(const float4*)bp;
        uint2 o0, o1;
        o0.x = cvtpk(acc0[nt][0] + bv.x, acc0[nt][1] + bv.y);
        o0.y = cvtpk(acc0[nt][2] + bv.z, acc0[nt][3] + bv.w);
        o1.x = cvtpk(acc1[nt][0] + bv.x, acc1[nt][1] + bv.y);
        o1.y = cvtpk(acc1[nt][2] + bv.z, acc1[nt][3] + bv.w);
        int nc = isL ? n0 : (n0 - 128);
        if (v0) {
            u16* dst = (isL ? xlb : xrb) + (size_t)mA0 * DIM + nc;
            *(uint2*)dst = o0;
        }
        if (v1) {
            u16* dst = (isL ? xlb : xrb) + (size_t)mA1 * DIM + nc;
            *(uint2*)dst = o1;
        }
    }

    if (blockIdx.x == 0 && tid < DIM) {
        float s = att[tid];
        xlb[(size_t)SENT * DIM + tid] = f2bf(s >= 0.f ? -10000.f : 10000.f);
    }
}

// ---------- fused edge phase: 1 node per 64-thread block, packed-f32 math ----------
#define PROC(U) do {                                                          \
    f32x2 x01 = bf2v((U).x), x23 = bf2v((U).y);                               \
    f32x2 x45 = bf2v((U).z), x67 = bf2v((U).w);                               \
    f32x2 z01 = x01 + xr01, z23 = x23 + xr23;                                 \
    f32x2 z45 = x45 + xr45, z67 = x67 + xr67;                                 \
    z01 = __builtin_elementwise_max(z01, z01 * negv);                         \
    z23 = __builtin_elementwise_max(z23, z23 * negv);                         \
    z45 = __builtin_elementwise_max(z45, z45 * negv);                         \
    z67 = __builtin_elementwise_max(z67, z67 * negv);                         \
    f32x2 pp2 = at01 * z01;                                                   \
    pp2 = at23 * z23 + pp2;                                                   \
    pp2 = at45 * z45 + pp2;                                                   \
    pp2 = at67 * z67 + pp2;                                                   \
    float pp = pp2.x + pp2.y;                                                 \
    pp = rradd<0x121>(pp);                                                    \
    pp = rradd<0x122>(pp);                                                    \
    pp = rradd<0x124>(pp);                                                    \
    pp = rradd<0x128>(pp);                                                    \
    float w_ = __builtin_amdgcn_exp2f(pp);                                    \
    lsum += w_;                                                               \
    f32x2 wv; wv.x = w_; wv.y = w_;                                           \
    ac01 = wv * x01 + ac01; ac23 = wv * x23 + ac23;                           \
    ac45 = wv * x45 + ac45; ac67 = wv * x67 + ac67;                           \
} while (0)

#define LDQ(U, Q) do {                                                        \
    u32 ob_ = __shfl(off, ((Q) << 2) + g, 64);                                \
    (U) = *(const uint4*)(xbp + (size_t)(ob_ + dofs));                        \
} while (0)

template <int RELU>
__global__ __launch_bounds__(64) void k_edge(
    const u16* __restrict__ xlb, const u16* __restrict__ xrb,
    const int* __restrict__ row_off, const u32* __restrict__ col,
    const float* __restrict__ att, const float* __restrict__ bias,
    u16* __restrict__ hout)
{
    const int node = blockIdx.x;
    const int lane = threadIdx.x & 63;
    const int g = lane >> 4;
    const int t = lane & 15;

    const int d0 = t * 8;
    const u32 dofs = (u32)(t << 4);
    const char* xbp = (const char*)xlb;

    uint4 xru = *(const uint4*)(xrb + (size_t)node * DIM + d0);
    f32x2 xr01 = bf2v(xru.x), xr23 = bf2v(xru.y), xr45 = bf2v(xru.z), xr67 = bf2v(xru.w);
    float2 a0 = *(const float2*)(att + d0);
    float2 a1 = *(const float2*)(att + d0 + 2);
    float2 a2 = *(const float2*)(att + d0 + 4);
    float2 a3 = *(const float2*)(att + d0 + 6);
    f32x2 at01, at23, at45, at67;
    at01.x = a0.x * LOG2E; at01.y = a0.y * LOG2E;
    at23.x = a1.x * LOG2E; at23.y = a1.y * LOG2E;
    at45.x = a2.x * LOG2E; at45.y = a2.y * LOG2E;
    at67.x = a3.x * LOG2E; at67.y = a3.y * LOG2E;
    f32x2 negv; negv.x = NEG; negv.y = NEG;

    const int beg = __builtin_amdgcn_readfirstlane(row_off[node]);
    const int end = __builtin_amdgcn_readfirstlane(row_off[node + 1]);
    const int n = end - beg;                 // padded: multiple of 4, >= 16
    const int nreg = (n < 64) ? n : 64;
    const int nq = nreg >> 2;                // >= 4 always

    u32 off = col[beg + lane];               // pre-scaled byte offsets

    f32x2 ac01, ac23, ac45, ac67;
    ac01.x = ac01.y = ac23.x = ac23.y = 0.f;
    ac45.x = ac45.y = ac67.x = ac67.y = 0.f;
    float lsum = 0.f;

    // prologue: 4 quads always valid -> unconditional prefetch
    uint4 u0, u1, u2, u3;
    LDQ(u0, 0); LDQ(u1, 1); LDQ(u2, 2); LDQ(u3, 3);

    // steady state: branch-free body, 4 loads always in flight
    int q = 0;
    for (; q + 8 <= nq; q += 4) {
        PROC(u0); LDQ(u0, q + 4);
        PROC(u1); LDQ(u1, q + 5);
        PROC(u2); LDQ(u2, q + 6);
        PROC(u3); LDQ(u3, q + 7);
    }
    // epilogue: 4..7 quads remain; wave-uniform scalar guards only
    PROC(u0); if (q + 4 < nq) LDQ(u0, q + 4);
    PROC(u1); if (q + 5 < nq) LDQ(u1, q + 5);
    PROC(u2); if (q + 6 < nq) LDQ(u2, q + 6);
    PROC(u3); if (q + 7 < nq) LDQ(u3, q + 7);
    q += 4;
    if (q     < nq) PROC(u0);
    if (q + 1 < nq) PROC(u1);
    if (q + 2 < nq) PROC(u2);

    // rare tail: rows longer than 64 (pads included; sentinel adds exactly 0)
    for (int j = beg + 64 + g; j < end; j += 4) {
        u32 ob_ = col[j];
        uint4 u = *(const uint4*)(xbp + (size_t)(ob_ + dofs));
        PROC(u);
    }

    // merge the 4 groups
    float accv[8] = {ac01.x, ac01.y, ac23.x, ac23.y, ac45.x, ac45.y, ac67.x, ac67.y};
#pragma unroll
    for (int i = 0; i < 8; ++i) {
        accv[i] += __shfl_xor(accv[i], 16, 64);
        accv[i] += __shfl_xor(accv[i], 32, 64);
    }
    lsum += __shfl_xor(lsum, 16, 64);
    lsum += __shfl_xor(lsum, 32, 64);

    if (g == 0) {
        float inv = 1.f / fmaxf(lsum, 1e-16f);
        float4 b0 = *(const float4*)(bias + d0);
        float4 b1 = *(const float4*)(bias + d0 + 4);
        float o0 = accv[0] * inv + b0.x;
        float o1 = accv[1] * inv + b0.y;
        float o2 = accv[2] * inv + b0.z;
        float o3 = accv[3] * inv + b0.w;
        float o4 = accv[4] * inv + b1.x;
        float o5 = accv[5] * inv + b1.y;
        float o6 = accv[6] * inv + b1.z;
        float o7 = accv[7] * inv + b1.w;
        if (RELU) {
            o0 = fmaxf(o0, 0.f); o1 = fmaxf(o1, 0.f);
            o2 = fmaxf(o2, 0.f); o3 = fmaxf(o3, 0.f);
            o4 = fmaxf(o4, 0.f); o5 = fmaxf(o5, 0.f);
            o6 = fmaxf(o6, 0.f); o7 = fmaxf(o7, 0.f);
        }
        uint4 o;
        o.x = cvtpk(o0, o1);
        o.y = cvtpk(o2, o3);
        o.z = cvtpk(o4, o5);
        o.w = cvtpk(o6, o7);
        *(uint4*)(hout + (size_t)node * DIM + d0) = o;
    }
}

// ---------- mean pool (bf16 h), vectorized uint4 loads ----------
__global__ __launch_bounds__(256) void k_mean_part(const u16* __restrict__ hb,
                                                   float* __restrict__ part) {
    __shared__ float sh[4][16][8];
    int t = threadIdx.x;
    int b = blockIdx.x;
    int c0 = (t & 15) * 8;
    int rl = t >> 4;
    int n0 = b * 400;
    float acc[8] = {0.f, 0.f, 0.f, 0.f, 0.f, 0.f, 0.f, 0.f};
    for (int i = 0; i < 25; ++i) {
        int r = n0 + rl + i * 16;
        uint4 v = *(const uint4*)(hb + (size_t)r * DIM + c0);
        f32x2 p0 = bf2v(v.x), p1 = bf2v(v.y), p2 = bf2v(v.z), p3 = bf2v(v.w);
        acc[0] += p0.x; acc[1] += p0.y;
        acc[2] += p1.x; acc[3] += p1.y;
        acc[4] += p2.x; acc[5] += p2.y;
        acc[6] += p3.x; acc[7] += p3.y;
    }
#pragma unroll
    for (int i = 0; i < 8; ++i) {
        acc[i] += __shfl_xor(acc[i], 16, 64);
        acc[i] += __shfl_xor(acc[i], 32, 64);
    }
    int wave = t >> 6;
    if ((t & 63) < 16) {
#pragma unroll
        for (int i = 0; i < 8; ++i) sh[wave][t & 15][i] = acc[i];
    }
    __syncthreads();
    if (t < 16) {
#pragma unroll
        for (int i = 0; i < 8; ++i) {
            float s = sh[0][t][i] + sh[1][t][i] + sh[2][t][i] + sh[3][t][i];
            part[b * DIM + t * 8 + i] = s;
        }
    }
}

__global__ void k_mean_final(const float* __restrict__ part, float* __restrict__ out) {
    int d = threadIdx.x;
    float s = 0.f;
    for (int b = 0; b < 125; ++b) s += part[b * DIM + d];
    out[d] = s * (1.f / (float)N_NODES);
}

// ---------- launch ----------
extern "C" void kernel_launch(void* const* d_in, const int* in_sizes, int n_in,
                              void* d_out, int out_size, void* d_ws, size_t ws_size,
                              hipStream_t stream) {
    int ix, iei, iWl, ibl, iWr, ibr, iatt, ibias;
    if (in_sizes[0] == N_NODES * DIM) {
        ix = 0; iei = 1; iWl = 2; ibl = 3; iWr = 4; ibr = 5; iatt = 6; ibias = 7;
    } else {
        iWl = 0; iWr = 1; iatt = 2; ibias = 3; ibl = 4; ibr = 5; iei = 6; ix = 7;
    }
    const float* x    = (const float*)d_in[ix];
    const void*  ei   = d_in[iei];
    const float* Wl   = (const float*)d_in[iWl];
    const float* bl   = (const float*)d_in[ibl];
    const float* Wr   = (const float*)d_in[iWr];
    const float* br   = (const float*)d_in[ibr];
    const float* att  = (const float*)d_in[iatt];
    const float* bias = (const float*)d_in[ibias];
    float* out = (float*)d_out;

    char* w = (char*)d_ws;
    float* part = (float*)w;      w += (size_t)256 * DIM * 4;
    uint4* Wtg = (uint4*)w;       w += (size_t)N_LAYERS * 4096 * 16;
    u16* xb  = (u16*)w;           w += (size_t)N_NODES * DIM * 2;
    u16* hb  = (u16*)w;           w += (size_t)N_NODES * DIM * 2;
    u16* xlb = (u16*)w;           w += (size_t)(N_NODES + 1) * DIM * 2;  // +1 sentinel row
    u16* xrb = (u16*)w;           w += (size_t)N_NODES * DIM * 2;
    int* row_off = (int*)w;       w += (size_t)(N_NODES + 4) * 4;
    int* flags = (int*)w;         w += 64;
    int* bcnt = (int*)w;          w += (size_t)(NBKT + 4) * 4;
    int* btot = (int*)w;          w += (size_t)(NBKT + 4) * 4;
    u32* bpk = (u32*)w;           w += (size_t)NBKT * BCAP_A * 4;
    u32* col = (u32*)w;           w += (size_t)(N_EDGES + 8 * N_NODES + 64) * 4;  // padded CSR, byte offsets

    k_cvt_x<<<(N_NODES * DIM / 2 + 255) / 256, 256, 0, stream>>>(x, xb);
    k_cvt_w<<<(N_LAYERS * 4096 + 255) / 256, 256, 0, stream>>>(Wl, Wr, Wtg,
                                                               (const int*)ei, flags, bcnt);
    k_part<<<PBLK, 1024, 0, stream>>>(ei, flags, bcnt, bpk);
    k_deg<<<NBKT, 256, 0, stream>>>(bpk, bcnt, ei, flags, row_off, btot);
    k_scat<<<NBKT, 256, 0, stream>>>(bpk, bcnt, row_off, btot, col, ei, flags);

    const int mm_grid = (N_NODES + 127) / 128;

    for (int layer = 0; layer < N_LAYERS; ++layer) {
        const uint4* Wp = Wtg + (size_t)layer * 4096;
        const float* blp = bl + (size_t)layer * DIM;
        const float* brp = br + (size_t)layer * DIM;
        const float* ap  = att + (size_t)layer * DIM;
        const float* bp  = bias + (size_t)layer * DIM;

        const u16* hin = (layer == 0) ? xb : hb;
        k_mm<<<mm_grid, 256, 0, stream>>>(hin, Wp, blp, brp, ap, xlb, xrb);

        if (layer < N_LAYERS - 1)
            k_edge<1><<<N_NODES, 64, 0, stream>>>(xlb, xrb, row_off, col, ap, bp, hb);
        else
            k_edge<0><<<N_NODES, 64, 0, stream>>>(xlb, xrb, row_off, col, ap, bp, hb);
    }

    k_mean_part<<<125, 256, 0, stream>>>(hb, part);
    k_mean_final<<<1, 128, 0, stream>>>(part, out);
}